// Round 1
// baseline (1640.740 us; speedup 1.0000x reference)
//
#include <hip/hip_runtime.h>
#include <cmath>
#include <cstdint>

// Problem constants (B=8, N=4096, C=1024, H=16, D=64, FF=4096)
#define MTOK 32768   // B*N tokens
#define CDIM 1024
#define SEQ  4096
#define NHEAD 16
#define HDIM 64
#define FFDIM 4096

typedef __attribute__((ext_vector_type(8))) short short8;   // 8 bf16 (4 VGPRs)
typedef __attribute__((ext_vector_type(4))) float f32x4;

static __device__ __forceinline__ float b2f(unsigned short u){
  union { unsigned int i; float f; } c; c.i = ((unsigned int)u)<<16; return c.f;
}
static __device__ __forceinline__ unsigned short f2b(float f){
  union { float f; unsigned int i; } c; c.f = f;
  return (unsigned short)((c.i + 0x7fffu + ((c.i>>16)&1u)) >> 16);  // RNE
}
// async global->LDS, 16B/lane; LDS dest = wave-uniform base + lane*16
static __device__ __forceinline__ void async16(const void* g, void* l){
  __builtin_amdgcn_global_load_lds((const __attribute__((address_space(1))) void*)g,
                                   (__attribute__((address_space(3))) void*)l, 16, 0, 0);
}

// ---------------- mask dtype detection + decode ----------------
// mask is [B,N] bool from JAX. Harness may upload as 1-byte bool or int32.
// View first 32768 bytes as u32 (in-bounds under both): bool8 padding runs
// produce words like 0x01010101 (>1); int32 {0,1} never exceeds 1.
__global__ void detect_mask_kernel(const unsigned int* __restrict__ m, int* __restrict__ flag){
  __shared__ int any;
  if(threadIdx.x==0) any=0;
  __syncthreads();
  int loc=0;
  for(int i=threadIdx.x;i<8192;i+=256) if(m[i]>1u) loc=1;
  if(loc) atomicOr(&any,1);
  __syncthreads();
  if(threadIdx.x==0) *flag=any;
}
__global__ void decode_mask_kernel(const void* __restrict__ m, const int* __restrict__ flag,
                                   float* __restrict__ validf){
  int i = blockIdx.x*256 + threadIdx.x;   // grid covers MTOK exactly
  int pad = (*flag) ? (int)((const unsigned char*)m)[i] : ((const int*)m)[i];
  validf[i] = pad ? 0.f : 1.f;
}

// ---------------- fp32 -> bf16 cast (weights) ----------------
__global__ void cast_bf16_kernel(const float* __restrict__ x, unsigned short* __restrict__ y, int n){
  int i = (blockIdx.x*256 + threadIdx.x)*4;
  if(i>=n) return;
  float4 v = *(const float4*)(x+i);
  ushort4 o; o.x=f2b(v.x); o.y=f2b(v.y); o.z=f2b(v.z); o.w=f2b(v.w);
  *(ushort4*)(y+i)=o;
}

// ---------------- LayerNorm (C=1024) -> bf16 ----------------
__global__ __launch_bounds__(256) void ln_kernel(const float* __restrict__ x,
    const float* __restrict__ g, const float* __restrict__ bt, unsigned short* __restrict__ out){
  int row = blockIdx.x, t = threadIdx.x;
  const float* xr = x + (size_t)row*CDIM;
  float4 v = *(const float4*)(xr + t*4);
  float s1 = v.x+v.y+v.z+v.w;
  float s2 = v.x*v.x+v.y*v.y+v.z*v.z+v.w*v.w;
  #pragma unroll
  for(int off=32; off>0; off>>=1){ s1+=__shfl_down(s1,off); s2+=__shfl_down(s2,off); }
  __shared__ float a1[4], a2[4];
  __shared__ float mu_s, rs_s;
  if((t&63)==0){ a1[t>>6]=s1; a2[t>>6]=s2; }
  __syncthreads();
  if(t==0){
    float u1=a1[0]+a1[1]+a1[2]+a1[3], u2=a2[0]+a2[1]+a2[2]+a2[3];
    float mu=u1*(1.f/CDIM);
    mu_s=mu; rs_s=rsqrtf(u2*(1.f/CDIM)-mu*mu+1e-5f);
  }
  __syncthreads();
  float mu=mu_s, rs=rs_s;
  float4 gg=*(const float4*)(g+t*4), bb=*(const float4*)(bt+t*4);
  ushort4 o;
  o.x=f2b((v.x-mu)*rs*gg.x+bb.x);
  o.y=f2b((v.y-mu)*rs*gg.y+bb.y);
  o.z=f2b((v.z-mu)*rs*gg.z+bb.z);
  o.w=f2b((v.w-mu)*rs*gg.w+bb.w);
  *(ushort4*)(out+(size_t)row*CDIM+t*4)=o;
}

// ---------------- GEMM: C[M,N] = A[M,K] * Bw[N,K]^T, bf16 in, fused epilogue ----
// MODE 0: QKV  -> Cb[m,3072] = phi/mask per column third (extra=validf, bias=qkv_b)
// MODE 1: XRES -> Cf[m,N] = acc + bias + extra[m,N]   (out-proj + residual, Cf=d_out)
// MODE 2: GELU -> Cb[m,N] = bf16(gelu_exact(acc+bias))
// MODE 3: ADD  -> Cf[m,N] += acc + bias               (FFN2 accumulate into x)
template<int MODE>
__global__ __launch_bounds__(256,2) void gemm_bt(
    const unsigned short* __restrict__ A, const unsigned short* __restrict__ Bw,
    const float* __restrict__ bias, const float* __restrict__ extra,
    float* __restrict__ Cf, unsigned short* __restrict__ Cb,
    int M, int N, int K)
{
  __shared__ __align__(16) unsigned short As[128*64];
  __shared__ __align__(16) unsigned short Bs[128*64];
  const int tid = threadIdx.x;
  const int wave = tid>>6, lane = tid&63;
  const int wm = wave>>1, wn = wave&1;          // 2x2 wave grid, 64x64 per wave
  const int m0 = blockIdx.y*128, n0 = blockIdx.x*128;
  const int lrow = lane>>3;                     // 0..7 rows within a wave-op
  const int lcol = (lane&7)*8;                  // 8 bf16 = 16B per lane

  f32x4 acc[4][4];
  #pragma unroll
  for(int i=0;i<4;i++)
    #pragma unroll
    for(int j=0;j<4;j++) acc[i][j]=(f32x4)(0.f);

  const int ar = wm*64 + (lane&15);             // A frag row in tile
  const int br = wn*64 + (lane&15);             // B frag row in tile
  const int ak = (lane>>4)*8;                   // k sub-offset within 32-step

  for(int kt=0; kt<K; kt+=64){
    #pragma unroll
    for(int it=0; it<4; it++){
      int wo = wave*4+it;                       // wave-op 0..15, 8 rows each
      int r  = wo*8 + lrow;
      async16(A  + (size_t)(m0+r)*K + kt + lcol, (void*)&As[wo*512]);
      async16(Bw + (size_t)(n0+r)*K + kt + lcol, (void*)&Bs[wo*512]);
    }
    __syncthreads();   // compiler drains vmcnt before s_barrier -> tiles ready
    #pragma unroll
    for(int ks=0; ks<2; ks++){
      short8 a[4], b[4];
      #pragma unroll
      for(int i=0;i<4;i++){
        a[i]=*(const short8*)&As[(ar+i*16)*64 + ks*32 + ak];
        b[i]=*(const short8*)&Bs[(br+i*16)*64 + ks*32 + ak];
      }
      #pragma unroll
      for(int i=0;i<4;i++)
        #pragma unroll
        for(int j=0;j<4;j++)
          acc[i][j]=__builtin_amdgcn_mfma_f32_16x16x32_bf16(a[i],b[j],acc[i][j],0,0,0);
    }
    __syncthreads();
  }
  // epilogue: C/D layout col=lane&15, row=(lane>>4)*4+reg
  const int rbase = m0 + wm*64 + (lane>>4)*4;
  const int cbase = n0 + wn*64 + (lane&15);
  #pragma unroll
  for(int mi=0;mi<4;mi++){
    #pragma unroll
    for(int i=0;i<4;i++){
      int m = rbase + mi*16 + i;
      #pragma unroll
      for(int ni=0;ni<4;ni++){
        int n = cbase + ni*16;
        float v = acc[mi][ni][i] + bias[n];
        if(MODE==0){
          float valid = extra[m];
          int part = n>>10;                      // 0=q,1=k,2=v
          float p = (v>0.f)? (v+1.f) : __expf(v);// phi = elu+1
          float r = (part==0)? p : (part==1? p*valid : v*valid);
          Cb[(size_t)m*N + n] = f2b(r);
        } else if(MODE==1){
          size_t off=(size_t)m*N+n;
          Cf[off] = v + extra[off];
        } else if(MODE==2){
          float gl = 0.5f*v*(1.f+erff(v*0.70710678118654752f));
          Cb[(size_t)m*N+n] = f2b(gl);
        } else {
          size_t off=(size_t)m*N+n;
          Cf[off] += v;
        }
      }
    }
  }
}

// ---------------- kv = phi(k)^T v, z = sum phi(k), partial over 256-row chunks ----
__global__ __launch_bounds__(256) void kvz_partial_kernel(
    const unsigned short* __restrict__ qkv, float* __restrict__ kvp, float* __restrict__ zp)
{
  const int chunk = blockIdx.x;   // 0..15 (256 rows each)
  const int bh = blockIdx.y;      // 0..127
  const int b = bh>>4, h = bh&15;
  const int t = threadIdx.x;
  __shared__ float kfs[16][64];
  __shared__ float vs[16][64];
  float acc[4][4]={{0}}; float zacc[4]={0};
  const int td=t&15, te=t>>4;
  const int d0=td*4, e0=te*4;
  const int lr=t>>4, lc=(t&15)*4;
  for(int s=0;s<16;s++){
    size_t m  = (size_t)(b*SEQ + chunk*256 + s*16 + lr);
    size_t rb = m*3072 + (size_t)h*64;
    ushort4 k4 = *(const ushort4*)(qkv + rb + 1024 + lc);
    ushort4 v4 = *(const ushort4*)(qkv + rb + 2048 + lc);
    __syncthreads();
    kfs[lr][lc]=b2f(k4.x); kfs[lr][lc+1]=b2f(k4.y); kfs[lr][lc+2]=b2f(k4.z); kfs[lr][lc+3]=b2f(k4.w);
    vs [lr][lc]=b2f(v4.x); vs [lr][lc+1]=b2f(v4.y); vs [lr][lc+2]=b2f(v4.z); vs [lr][lc+3]=b2f(v4.w);
    __syncthreads();
    #pragma unroll
    for(int n=0;n<16;n++){
      float4 kq=*(const float4*)&kfs[n][d0];
      float4 vv=*(const float4*)&vs[n][e0];
      float kqa[4]={kq.x,kq.y,kq.z,kq.w};
      float vva[4]={vv.x,vv.y,vv.z,vv.w};
      #pragma unroll
      for(int i=0;i<4;i++)
        #pragma unroll
        for(int j=0;j<4;j++) acc[i][j]+=kqa[i]*vva[j];
      if(te==0){ zacc[0]+=kq.x; zacc[1]+=kq.y; zacc[2]+=kq.z; zacc[3]+=kq.w; }
    }
  }
  const int pidx = bh*16 + chunk;
  float* kvd = kvp + (size_t)pidx*4096;
  #pragma unroll
  for(int i=0;i<4;i++){
    float4 o={acc[i][0],acc[i][1],acc[i][2],acc[i][3]};
    *(float4*)(kvd + (d0+i)*64 + e0)=o;
  }
  if(te==0){
    float4 o={zacc[0],zacc[1],zacc[2],zacc[3]};
    *(float4*)(zp + (size_t)pidx*64 + d0)=o;
  }
}

__global__ void kvz_reduce_kernel(const float* __restrict__ kvp, const float* __restrict__ zp,
                                  float* __restrict__ kv, float* __restrict__ z){
  int bh = blockIdx.x, t = threadIdx.x;
  for(int j=t; j<4096; j+=256){
    float s=0;
    for(int c=0;c<16;c++) s += kvp[((size_t)bh*16+c)*4096 + j];
    kv[(size_t)bh*4096 + j] = s;
  }
  if(t<64){
    float s=0;
    for(int c=0;c<16;c++) s += zp[((size_t)bh*16+c)*64 + t];
    z[bh*64+t]=s;
  }
}

// ---------------- y = (qf @ kv) / max(qf . z, eps) -> bf16 [MTOK, 1024] ----------
__global__ __launch_bounds__(256) void y_kernel(
    const unsigned short* __restrict__ qkv, const float* __restrict__ kv,
    const float* __restrict__ z, unsigned short* __restrict__ ybuf)
{
  const int nch = blockIdx.x;   // 0..63 (64 rows each)
  const int bh  = blockIdx.y;   // 0..127
  const int b = bh>>4, h = bh&15;
  const int t = threadIdx.x;
  __shared__ float kvs[64][64];
  __shared__ float qfs[64][68];  // padded: breaks 4-way bank conflict on column reads
  __shared__ float zs[64];
  // stage kv (fp32) and z
  for(int j=t*4; j<4096; j+=1024){
    float4 vv=*(const float4*)(kv+(size_t)bh*4096+j);
    ((float*)kvs)[j]=vv.x; ((float*)kvs)[j+1]=vv.y; ((float*)kvs)[j+2]=vv.z; ((float*)kvs)[j+3]=vv.w;
  }
  if(t<64) zs[t]=z[bh*64+t];
  // stage qf tile (64 rows x 64 d)
  for(int s=0;s<4;s++){
    int row=s*16+(t>>4), col=(t&15)*4;
    size_t m=(size_t)(b*SEQ+nch*64+row);
    ushort4 q4=*(const ushort4*)(qkv+m*3072+(size_t)h*64+col);
    qfs[row][col]=b2f(q4.x); qfs[row][col+1]=b2f(q4.y); qfs[row][col+2]=b2f(q4.z); qfs[row][col+3]=b2f(q4.w);
  }
  __syncthreads();
  const int tn=t>>4, te=t&15;
  const int nr0=tn*4, e0=te*4;
  float acc[4][4]={{0}}; float den[4]={0};
  #pragma unroll 4
  for(int d=0;d<64;d++){
    float4 kv4=*(const float4*)&kvs[d][e0];
    float zd=zs[d];
    #pragma unroll
    for(int i=0;i<4;i++){
      float q=qfs[nr0+i][d];
      acc[i][0]+=q*kv4.x; acc[i][1]+=q*kv4.y; acc[i][2]+=q*kv4.z; acc[i][3]+=q*kv4.w;
      den[i]+=q*zd;
    }
  }
  #pragma unroll
  for(int i=0;i<4;i++){
    float inv=1.f/fmaxf(den[i],1e-6f);
    ushort4 o;
    o.x=f2b(acc[i][0]*inv); o.y=f2b(acc[i][1]*inv); o.z=f2b(acc[i][2]*inv); o.w=f2b(acc[i][3]*inv);
    size_t m=(size_t)(b*SEQ+nch*64+nr0+i);
    *(ushort4*)(ybuf+m*1024+(size_t)h*64+e0)=o;
  }
}

extern "C" void kernel_launch(void* const* d_in, const int* in_sizes, int n_in,
                              void* d_out, int out_size, void* d_ws, size_t ws_size,
                              hipStream_t stream)
{
  const float* src   = (const float*)d_in[0];
  const void*  mask  = d_in[1];
  const float* qkv_w = (const float*)d_in[2];
  const float* qkv_b = (const float*)d_in[3];
  const float* out_w = (const float*)d_in[4];
  const float* out_b = (const float*)d_in[5];
  const float* w1    = (const float*)d_in[6];
  const float* b1    = (const float*)d_in[7];
  const float* w2    = (const float*)d_in[8];
  const float* b2    = (const float*)d_in[9];
  const float* ln1g  = (const float*)d_in[10];
  const float* ln1b  = (const float*)d_in[11];
  const float* ln2g  = (const float*)d_in[12];
  const float* ln2b  = (const float*)d_in[13];
  float* out = (float*)d_out;
  char* ws = (char*)d_ws;

  // workspace layout (~346 MiB total)
  size_t o = 0;
  int* flag = (int*)(ws);                         o += 256;
  float* validf = (float*)(ws+o);                 o += (size_t)MTOK*4;
  unsigned short* wqb = (unsigned short*)(ws+o);  o += (size_t)3072*1024*2;
  unsigned short* wob = (unsigned short*)(ws+o);  o += (size_t)1024*1024*2;
  unsigned short* w1b = (unsigned short*)(ws+o);  o += (size_t)4096*1024*2;
  unsigned short* w2b = (unsigned short*)(ws+o);  o += (size_t)1024*4096*2;
  unsigned short* bufA = (unsigned short*)(ws+o); o += (size_t)MTOK*1024*2;       // ln1 -> y -> ln2
  char* R = ws+o;                                 o += (size_t)MTOK*4096*2;       // qkv (201MB) then h (268MB)
  unsigned short* qkvbuf = (unsigned short*)R;
  float* kvp = (float*)(R + (size_t)MTOK*3072*2);                                  // fits in R tail
  float* zp  = (float*)(R + (size_t)MTOK*3072*2 + (size_t)2048*4096*4);
  unsigned short* hbuf = (unsigned short*)R;
  float* kv = (float*)(ws+o);                     o += (size_t)128*4096*4;
  float* zv = (float*)(ws+o);                     o += (size_t)128*64*4;

  detect_mask_kernel<<<1,256,0,stream>>>((const unsigned int*)mask, flag);
  decode_mask_kernel<<<MTOK/256,256,0,stream>>>(mask, flag, validf);
  cast_bf16_kernel<<<3072,256,0,stream>>>(qkv_w, wqb, 3072*1024);
  cast_bf16_kernel<<<1024,256,0,stream>>>(out_w, wob, 1024*1024);
  cast_bf16_kernel<<<4096,256,0,stream>>>(w1,  w1b, 4096*1024);
  cast_bf16_kernel<<<8192,256,0,stream>>>(w2,  w2b, 1024*4096);

  ln_kernel<<<MTOK,256,0,stream>>>(src, ln1g, ln1b, bufA);
  gemm_bt<0><<<dim3(3072/128, MTOK/128),256,0,stream>>>(bufA, wqb, qkv_b, validf, nullptr, qkvbuf, MTOK,3072,1024);
  kvz_partial_kernel<<<dim3(16,128),256,0,stream>>>(qkvbuf, kvp, zp);
  kvz_reduce_kernel<<<128,256,0,stream>>>(kvp, zp, kv, zv);
  y_kernel<<<dim3(64,128),256,0,stream>>>(qkvbuf, kv, zv, bufA);
  gemm_bt<1><<<dim3(1024/128, MTOK/128),256,0,stream>>>(bufA, wob, out_b, src, out, nullptr, MTOK,1024,1024);
  ln_kernel<<<MTOK,256,0,stream>>>(out, ln2g, ln2b, bufA);
  gemm_bt<2><<<dim3(4096/128, MTOK/128),256,0,stream>>>(bufA, w1b, b1, nullptr, nullptr, hbuf, MTOK,4096,1024);
  gemm_bt<3><<<dim3(1024/128, MTOK/128),256,0,stream>>>(hbuf, w2b, b2, nullptr, out, nullptr, MTOK,1024,4096);
}

// Round 2
// 1478.386 us; speedup vs baseline: 1.1098x; 1.1098x over previous
//
#include <hip/hip_runtime.h>
#include <cmath>
#include <cstdint>

// Problem constants (B=8, N=4096, C=1024, H=16, D=64, FF=4096)
#define MTOK 32768   // B*N tokens
#define CDIM 1024
#define SEQ  4096
#define NHEAD 16
#define HDIM 64
#define FFDIM 4096

typedef __attribute__((ext_vector_type(8))) short short8;   // 8 bf16 (4 VGPRs)
typedef __attribute__((ext_vector_type(4))) float f32x4;

static __device__ __forceinline__ float b2f(unsigned short u){
  union { unsigned int i; float f; } c; c.i = ((unsigned int)u)<<16; return c.f;
}
static __device__ __forceinline__ unsigned short f2b(float f){
  union { float f; unsigned int i; } c; c.f = f;
  return (unsigned short)((c.i + 0x7fffu + ((c.i>>16)&1u)) >> 16);  // RNE
}
// async global->LDS, 16B/lane; LDS dest = wave-uniform base + lane*16
static __device__ __forceinline__ void async16(const void* g, void* l){
  __builtin_amdgcn_global_load_lds((const __attribute__((address_space(1))) void*)g,
                                   (__attribute__((address_space(3))) void*)l, 16, 0, 0);
}

// ---------------- mask dtype detection + decode ----------------
__global__ void detect_mask_kernel(const unsigned int* __restrict__ m, int* __restrict__ flag){
  __shared__ int any;
  if(threadIdx.x==0) any=0;
  __syncthreads();
  int loc=0;
  for(int i=threadIdx.x;i<8192;i+=256) if(m[i]>1u) loc=1;
  if(loc) atomicOr(&any,1);
  __syncthreads();
  if(threadIdx.x==0) *flag=any;
}
__global__ void decode_mask_kernel(const void* __restrict__ m, const int* __restrict__ flag,
                                   float* __restrict__ validf){
  int i = blockIdx.x*256 + threadIdx.x;   // grid covers MTOK exactly
  int pad = (*flag) ? (int)((const unsigned char*)m)[i] : ((const int*)m)[i];
  validf[i] = pad ? 0.f : 1.f;
}

// ---------------- fp32 -> bf16 cast (weights) ----------------
__global__ void cast_bf16_kernel(const float* __restrict__ x, unsigned short* __restrict__ y, int n){
  int i = (blockIdx.x*256 + threadIdx.x)*4;
  if(i>=n) return;
  float4 v = *(const float4*)(x+i);
  ushort4 o; o.x=f2b(v.x); o.y=f2b(v.y); o.z=f2b(v.z); o.w=f2b(v.w);
  *(ushort4*)(y+i)=o;
}

// ---------------- LayerNorm (C=1024) -> bf16 ----------------
__global__ __launch_bounds__(256) void ln_kernel(const float* __restrict__ x,
    const float* __restrict__ g, const float* __restrict__ bt, unsigned short* __restrict__ out){
  int row = blockIdx.x, t = threadIdx.x;
  const float* xr = x + (size_t)row*CDIM;
  float4 v = *(const float4*)(xr + t*4);
  float s1 = v.x+v.y+v.z+v.w;
  float s2 = v.x*v.x+v.y*v.y+v.z*v.z+v.w*v.w;
  #pragma unroll
  for(int off=32; off>0; off>>=1){ s1+=__shfl_down(s1,off); s2+=__shfl_down(s2,off); }
  __shared__ float a1[4], a2[4];
  __shared__ float mu_s, rs_s;
  if((t&63)==0){ a1[t>>6]=s1; a2[t>>6]=s2; }
  __syncthreads();
  if(t==0){
    float u1=a1[0]+a1[1]+a1[2]+a1[3], u2=a2[0]+a2[1]+a2[2]+a2[3];
    float mu=u1*(1.f/CDIM);
    mu_s=mu; rs_s=rsqrtf(u2*(1.f/CDIM)-mu*mu+1e-5f);
  }
  __syncthreads();
  float mu=mu_s, rs=rs_s;
  float4 gg=*(const float4*)(g+t*4), bb=*(const float4*)(bt+t*4);
  ushort4 o;
  o.x=f2b((v.x-mu)*rs*gg.x+bb.x);
  o.y=f2b((v.y-mu)*rs*gg.y+bb.y);
  o.z=f2b((v.z-mu)*rs*gg.z+bb.z);
  o.w=f2b((v.w-mu)*rs*gg.w+bb.w);
  *(ushort4*)(out+(size_t)row*CDIM+t*4)=o;
}

// ---------------- GEMM: C[M,N] = A[M,K] * Bw[N,K]^T, bf16 in, fused epilogue ----
// LDS layout XOR-swizzled: chunk c (8 bf16 = 16B) of row r stored at chunk c^(r&7).
// Staging keeps the wave-uniform-base+lane*16 LDS dest of global_load_lds and
// permutes the GLOBAL source column instead (within one 128B row segment, so
// coalescing is preserved). Fragment reads then spread 64 lanes over all 8
// 4-bank groups (8 accesses/bank = b128 conflict-free minimum).
// MODE 0: QKV  -> Cb[m,3072] = phi/mask per column third (extra=validf, bias=qkv_b)
// MODE 1: XRES -> Cf[m,N] = acc + bias + extra[m,N]   (out-proj + residual, Cf=d_out)
// MODE 2: GELU -> Cb[m,N] = bf16(gelu_exact(acc+bias))
// MODE 3: ADD  -> Cf[m,N] += acc + bias               (FFN2 accumulate into x)
template<int MODE>
__global__ __launch_bounds__(256,2) void gemm_bt(
    const unsigned short* __restrict__ A, const unsigned short* __restrict__ Bw,
    const float* __restrict__ bias, const float* __restrict__ extra,
    float* __restrict__ Cf, unsigned short* __restrict__ Cb,
    int M, int N, int K)
{
  __shared__ __align__(16) unsigned short As[128*64];
  __shared__ __align__(16) unsigned short Bs[128*64];
  const int tid = threadIdx.x;
  const int wave = tid>>6, lane = tid&63;
  const int wm = wave>>1, wn = wave&1;          // 2x2 wave grid, 64x64 per wave
  const int m0 = blockIdx.y*128, n0 = blockIdx.x*128;
  const int lrow = lane>>3;                     // 0..7 rows within a wave-op
  const int gcol = (((lane&7) ^ lrow))*8;       // swizzled global chunk for staging

  f32x4 acc[4][4];
  #pragma unroll
  for(int i=0;i<4;i++)
    #pragma unroll
    for(int j=0;j<4;j++) acc[i][j]=(f32x4)(0.f);

  const int ar = wm*64 + (lane&15);             // A frag row in tile
  const int br = wn*64 + (lane&15);             // B frag row in tile
  const int kc = lane>>4;                       // k chunk sub-index (0..3)
  const int xorv = lane&7;                      // row&7 == lane&7 for all frags

  for(int kt=0; kt<K; kt+=64){
    #pragma unroll
    for(int it=0; it<4; it++){
      int wo = wave*4+it;                       // wave-op 0..15, 8 rows each
      int r  = wo*8 + lrow;
      async16(A  + (size_t)(m0+r)*K + kt + gcol, (void*)&As[wo*512]);
      async16(Bw + (size_t)(n0+r)*K + kt + gcol, (void*)&Bs[wo*512]);
    }
    __syncthreads();   // compiler drains vmcnt before s_barrier -> tiles ready
    #pragma unroll
    for(int ks=0; ks<2; ks++){
      const int ch = ((ks*4 + kc) ^ xorv)*8;    // swizzled LDS chunk offset
      short8 a[4], b[4];
      #pragma unroll
      for(int i=0;i<4;i++){
        a[i]=*(const short8*)&As[(ar+i*16)*64 + ch];
        b[i]=*(const short8*)&Bs[(br+i*16)*64 + ch];
      }
      #pragma unroll
      for(int i=0;i<4;i++)
        #pragma unroll
        for(int j=0;j<4;j++)
          acc[i][j]=__builtin_amdgcn_mfma_f32_16x16x32_bf16(a[i],b[j],acc[i][j],0,0,0);
    }
    __syncthreads();
  }
  // epilogue: C/D layout col=lane&15, row=(lane>>4)*4+reg
  const int rbase = m0 + wm*64 + (lane>>4)*4;
  const int cbase = n0 + wn*64 + (lane&15);
  #pragma unroll
  for(int mi=0;mi<4;mi++){
    #pragma unroll
    for(int i=0;i<4;i++){
      int m = rbase + mi*16 + i;
      #pragma unroll
      for(int ni=0;ni<4;ni++){
        int n = cbase + ni*16;
        float v = acc[mi][ni][i] + bias[n];
        if(MODE==0){
          float valid = extra[m];
          int part = n>>10;                      // 0=q,1=k,2=v
          float p = (v>0.f)? (v+1.f) : __expf(v);// phi = elu+1
          float r = (part==0)? p : (part==1? p*valid : v*valid);
          Cb[(size_t)m*N + n] = f2b(r);
        } else if(MODE==1){
          size_t off=(size_t)m*N+n;
          Cf[off] = v + extra[off];
        } else if(MODE==2){
          float gl = 0.5f*v*(1.f+erff(v*0.70710678118654752f));
          Cb[(size_t)m*N+n] = f2b(gl);
        } else {
          size_t off=(size_t)m*N+n;
          Cf[off] += v;
        }
      }
    }
  }
}

// ---------------- kv = phi(k)^T v, z = sum phi(k), partial over 256-row chunks ----
__global__ __launch_bounds__(256) void kvz_partial_kernel(
    const unsigned short* __restrict__ qkv, float* __restrict__ kvp, float* __restrict__ zp)
{
  const int chunk = blockIdx.x;   // 0..15 (256 rows each)
  const int bh = blockIdx.y;      // 0..127
  const int b = bh>>4, h = bh&15;
  const int t = threadIdx.x;
  __shared__ float kfs[16][64];
  __shared__ float vs[16][64];
  float acc[4][4]={{0}}; float zacc[4]={0};
  const int td=t&15, te=t>>4;
  const int d0=td*4, e0=te*4;
  const int lr=t>>4, lc=(t&15)*4;
  for(int s=0;s<16;s++){
    size_t m  = (size_t)(b*SEQ + chunk*256 + s*16 + lr);
    size_t rb = m*3072 + (size_t)h*64;
    ushort4 k4 = *(const ushort4*)(qkv + rb + 1024 + lc);
    ushort4 v4 = *(const ushort4*)(qkv + rb + 2048 + lc);
    __syncthreads();
    kfs[lr][lc]=b2f(k4.x); kfs[lr][lc+1]=b2f(k4.y); kfs[lr][lc+2]=b2f(k4.z); kfs[lr][lc+3]=b2f(k4.w);
    vs [lr][lc]=b2f(v4.x); vs [lr][lc+1]=b2f(v4.y); vs [lr][lc+2]=b2f(v4.z); vs [lr][lc+3]=b2f(v4.w);
    __syncthreads();
    #pragma unroll
    for(int n=0;n<16;n++){
      float4 kq=*(const float4*)&kfs[n][d0];
      float4 vv=*(const float4*)&vs[n][e0];
      float kqa[4]={kq.x,kq.y,kq.z,kq.w};
      float vva[4]={vv.x,vv.y,vv.z,vv.w};
      #pragma unroll
      for(int i=0;i<4;i++)
        #pragma unroll
        for(int j=0;j<4;j++) acc[i][j]+=kqa[i]*vva[j];
      if(te==0){ zacc[0]+=kq.x; zacc[1]+=kq.y; zacc[2]+=kq.z; zacc[3]+=kq.w; }
    }
  }
  const int pidx = bh*16 + chunk;
  float* kvd = kvp + (size_t)pidx*4096;
  #pragma unroll
  for(int i=0;i<4;i++){
    float4 o={acc[i][0],acc[i][1],acc[i][2],acc[i][3]};
    *(float4*)(kvd + (d0+i)*64 + e0)=o;
  }
  if(te==0){
    float4 o={zacc[0],zacc[1],zacc[2],zacc[3]};
    *(float4*)(zp + (size_t)pidx*64 + d0)=o;
  }
}

__global__ void kvz_reduce_kernel(const float* __restrict__ kvp, const float* __restrict__ zp,
                                  float* __restrict__ kv, float* __restrict__ z){
  int bh = blockIdx.x, t = threadIdx.x;
  for(int j=t; j<4096; j+=256){
    float s=0;
    for(int c=0;c<16;c++) s += kvp[((size_t)bh*16+c)*4096 + j];
    kv[(size_t)bh*4096 + j] = s;
  }
  if(t<64){
    float s=0;
    for(int c=0;c<16;c++) s += zp[((size_t)bh*16+c)*64 + t];
    z[bh*64+t]=s;
  }
}

// ---------------- y = (qf @ kv) / max(qf . z, eps) -> bf16 [MTOK, 1024] ----------
__global__ __launch_bounds__(256) void y_kernel(
    const unsigned short* __restrict__ qkv, const float* __restrict__ kv,
    const float* __restrict__ z, unsigned short* __restrict__ ybuf)
{
  const int nch = blockIdx.x;   // 0..63 (64 rows each)
  const int bh  = blockIdx.y;   // 0..127
  const int b = bh>>4, h = bh&15;
  const int t = threadIdx.x;
  __shared__ float kvs[64][64];
  __shared__ float qfs[64][68];  // padded: breaks 4-way bank conflict on column reads
  __shared__ float zs[64];
  // stage kv (fp32) and z
  for(int j=t*4; j<4096; j+=1024){
    float4 vv=*(const float4*)(kv+(size_t)bh*4096+j);
    ((float*)kvs)[j]=vv.x; ((float*)kvs)[j+1]=vv.y; ((float*)kvs)[j+2]=vv.z; ((float*)kvs)[j+3]=vv.w;
  }
  if(t<64) zs[t]=z[bh*64+t];
  // stage qf tile (64 rows x 64 d)
  for(int s=0;s<4;s++){
    int row=s*16+(t>>4), col=(t&15)*4;
    size_t m=(size_t)(b*SEQ+nch*64+row);
    ushort4 q4=*(const ushort4*)(qkv+m*3072+(size_t)h*64+col);
    qfs[row][col]=b2f(q4.x); qfs[row][col+1]=b2f(q4.y); qfs[row][col+2]=b2f(q4.z); qfs[row][col+3]=b2f(q4.w);
  }
  __syncthreads();
  const int tn=t>>4, te=t&15;
  const int nr0=tn*4, e0=te*4;
  float acc[4][4]={{0}}; float den[4]={0};
  #pragma unroll 4
  for(int d=0;d<64;d++){
    float4 kv4=*(const float4*)&kvs[d][e0];
    float zd=zs[d];
    #pragma unroll
    for(int i=0;i<4;i++){
      float q=qfs[nr0+i][d];
      acc[i][0]+=q*kv4.x; acc[i][1]+=q*kv4.y; acc[i][2]+=q*kv4.z; acc[i][3]+=q*kv4.w;
      den[i]+=q*zd;
    }
  }
  #pragma unroll
  for(int i=0;i<4;i++){
    float inv=1.f/fmaxf(den[i],1e-6f);
    ushort4 o;
    o.x=f2b(acc[i][0]*inv); o.y=f2b(acc[i][1]*inv); o.z=f2b(acc[i][2]*inv); o.w=f2b(acc[i][3]*inv);
    size_t m=(size_t)(b*SEQ+nch*64+nr0+i);
    *(ushort4*)(ybuf+m*1024+(size_t)h*64+e0)=o;
  }
}

extern "C" void kernel_launch(void* const* d_in, const int* in_sizes, int n_in,
                              void* d_out, int out_size, void* d_ws, size_t ws_size,
                              hipStream_t stream)
{
  const float* src   = (const float*)d_in[0];
  const void*  mask  = d_in[1];
  const float* qkv_w = (const float*)d_in[2];
  const float* qkv_b = (const float*)d_in[3];
  const float* out_w = (const float*)d_in[4];
  const float* out_b = (const float*)d_in[5];
  const float* w1    = (const float*)d_in[6];
  const float* b1    = (const float*)d_in[7];
  const float* w2    = (const float*)d_in[8];
  const float* b2    = (const float*)d_in[9];
  const float* ln1g  = (const float*)d_in[10];
  const float* ln1b  = (const float*)d_in[11];
  const float* ln2g  = (const float*)d_in[12];
  const float* ln2b  = (const float*)d_in[13];
  float* out = (float*)d_out;
  char* ws = (char*)d_ws;

  // workspace layout (~346 MiB total)
  size_t o = 0;
  int* flag = (int*)(ws);                         o += 256;
  float* validf = (float*)(ws+o);                 o += (size_t)MTOK*4;
  unsigned short* wqb = (unsigned short*)(ws+o);  o += (size_t)3072*1024*2;
  unsigned short* wob = (unsigned short*)(ws+o);  o += (size_t)1024*1024*2;
  unsigned short* w1b = (unsigned short*)(ws+o);  o += (size_t)4096*1024*2;
  unsigned short* w2b = (unsigned short*)(ws+o);  o += (size_t)1024*4096*2;
  unsigned short* bufA = (unsigned short*)(ws+o); o += (size_t)MTOK*1024*2;       // ln1 -> y -> ln2
  char* R = ws+o;                                 o += (size_t)MTOK*4096*2;       // qkv (201MB) then h (268MB)
  unsigned short* qkvbuf = (unsigned short*)R;
  float* kvp = (float*)(R + (size_t)MTOK*3072*2);                                  // fits in R tail
  float* zp  = (float*)(R + (size_t)MTOK*3072*2 + (size_t)2048*4096*4);
  unsigned short* hbuf = (unsigned short*)R;
  float* kv = (float*)(ws+o);                     o += (size_t)128*4096*4;
  float* zv = (float*)(ws+o);                     o += (size_t)128*64*4;

  detect_mask_kernel<<<1,256,0,stream>>>((const unsigned int*)mask, flag);
  decode_mask_kernel<<<MTOK/256,256,0,stream>>>(mask, flag, validf);
  cast_bf16_kernel<<<3072,256,0,stream>>>(qkv_w, wqb, 3072*1024);
  cast_bf16_kernel<<<1024,256,0,stream>>>(out_w, wob, 1024*1024);
  cast_bf16_kernel<<<4096,256,0,stream>>>(w1,  w1b, 4096*1024);
  cast_bf16_kernel<<<8192,256,0,stream>>>(w2,  w2b, 1024*4096);

  ln_kernel<<<MTOK,256,0,stream>>>(src, ln1g, ln1b, bufA);
  gemm_bt<0><<<dim3(3072/128, MTOK/128),256,0,stream>>>(bufA, wqb, qkv_b, validf, nullptr, qkvbuf, MTOK,3072,1024);
  kvz_partial_kernel<<<dim3(16,128),256,0,stream>>>(qkvbuf, kvp, zp);
  kvz_reduce_kernel<<<128,256,0,stream>>>(kvp, zp, kv, zv);
  y_kernel<<<dim3(64,128),256,0,stream>>>(qkvbuf, kv, zv, bufA);
  gemm_bt<1><<<dim3(1024/128, MTOK/128),256,0,stream>>>(bufA, wob, out_b, src, out, nullptr, MTOK,1024,1024);
  ln_kernel<<<MTOK,256,0,stream>>>(out, ln2g, ln2b, bufA);
  gemm_bt<2><<<dim3(4096/128, MTOK/128),256,0,stream>>>(bufA, w1b, b1, nullptr, nullptr, hbuf, MTOK,4096,1024);
  gemm_bt<3><<<dim3(1024/128, MTOK/128),256,0,stream>>>(hbuf, w2b, b2, nullptr, out, nullptr, MTOK,1024,4096);
}

// Round 3
// 1442.279 us; speedup vs baseline: 1.1376x; 1.0250x over previous
//
#include <hip/hip_runtime.h>
#include <cmath>
#include <cstdint>

// Problem constants (B=8, N=4096, C=1024, H=16, D=64, FF=4096)
#define MTOK 32768   // B*N tokens
#define CDIM 1024
#define SEQ  4096
#define NHEAD 16
#define HDIM 64
#define FFDIM 4096

typedef __attribute__((ext_vector_type(8))) short short8;   // 8 bf16 (4 VGPRs)
typedef __attribute__((ext_vector_type(4))) float f32x4;

static __device__ __forceinline__ float b2f(unsigned short u){
  union { unsigned int i; float f; } c; c.i = ((unsigned int)u)<<16; return c.f;
}
static __device__ __forceinline__ unsigned short f2b(float f){
  union { float f; unsigned int i; } c; c.f = f;
  return (unsigned short)((c.i + 0x7fffu + ((c.i>>16)&1u)) >> 16);  // RNE
}
// async global->LDS, 16B/lane; LDS dest = wave-uniform base + lane*16
static __device__ __forceinline__ void async16(const void* g, void* l){
  __builtin_amdgcn_global_load_lds((const __attribute__((address_space(1))) void*)g,
                                   (__attribute__((address_space(3))) void*)l, 16, 0, 0);
}

// ---------------- mask dtype detection + decode ----------------
__global__ void detect_mask_kernel(const unsigned int* __restrict__ m, int* __restrict__ flag){
  __shared__ int any;
  if(threadIdx.x==0) any=0;
  __syncthreads();
  int loc=0;
  for(int i=threadIdx.x;i<8192;i+=256) if(m[i]>1u) loc=1;
  if(loc) atomicOr(&any,1);
  __syncthreads();
  if(threadIdx.x==0) *flag=any;
}
__global__ void decode_mask_kernel(const void* __restrict__ m, const int* __restrict__ flag,
                                   float* __restrict__ validf){
  int i = blockIdx.x*256 + threadIdx.x;   // grid covers MTOK exactly
  int pad = (*flag) ? (int)((const unsigned char*)m)[i] : ((const int*)m)[i];
  validf[i] = pad ? 0.f : 1.f;
}

// ---------------- fp32 -> bf16 cast (weights) ----------------
__global__ void cast_bf16_kernel(const float* __restrict__ x, unsigned short* __restrict__ y, int n){
  int i = (blockIdx.x*256 + threadIdx.x)*4;
  if(i>=n) return;
  float4 v = *(const float4*)(x+i);
  ushort4 o; o.x=f2b(v.x); o.y=f2b(v.y); o.z=f2b(v.z); o.w=f2b(v.w);
  *(ushort4*)(y+i)=o;
}

// ---------------- LayerNorm (C=1024) -> bf16 ----------------
__global__ __launch_bounds__(256) void ln_kernel(const float* __restrict__ x,
    const float* __restrict__ g, const float* __restrict__ bt, unsigned short* __restrict__ out){
  int row = blockIdx.x, t = threadIdx.x;
  const float* xr = x + (size_t)row*CDIM;
  float4 v = *(const float4*)(xr + t*4);
  float s1 = v.x+v.y+v.z+v.w;
  float s2 = v.x*v.x+v.y*v.y+v.z*v.z+v.w*v.w;
  #pragma unroll
  for(int off=32; off>0; off>>=1){ s1+=__shfl_down(s1,off); s2+=__shfl_down(s2,off); }
  __shared__ float a1[4], a2[4];
  __shared__ float mu_s, rs_s;
  if((t&63)==0){ a1[t>>6]=s1; a2[t>>6]=s2; }
  __syncthreads();
  if(t==0){
    float u1=a1[0]+a1[1]+a1[2]+a1[3], u2=a2[0]+a2[1]+a2[2]+a2[3];
    float mu=u1*(1.f/CDIM);
    mu_s=mu; rs_s=rsqrtf(u2*(1.f/CDIM)-mu*mu+1e-5f);
  }
  __syncthreads();
  float mu=mu_s, rs=rs_s;
  float4 gg=*(const float4*)(g+t*4), bb=*(const float4*)(bt+t*4);
  ushort4 o;
  o.x=f2b((v.x-mu)*rs*gg.x+bb.x);
  o.y=f2b((v.y-mu)*rs*gg.y+bb.y);
  o.z=f2b((v.z-mu)*rs*gg.z+bb.z);
  o.w=f2b((v.w-mu)*rs*gg.w+bb.w);
  *(ushort4*)(out+(size_t)row*CDIM+t*4)=o;
}

// ---------------- GEMM: C[M,N] = A[M,K] * Bw[N,K]^T, bf16 in, fused epilogue ----
// LDS layout XOR-swizzled: chunk c (8 bf16 = 16B) of row r stored at chunk c^(r&7)
// (conflict-free b128 reads; global source column permuted to keep the
// wave-uniform-base global_load_lds dest).
// XCD-aware block remap: wg->XCD is id%8, so map linear id f such that each XCD
// owns row-panels y==xcd (mod 8) and walks one row-panel's column-blocks
// consecutively -> A-panel fetched from HBM once per XCD (then L2 hits), B
// stays L3-resident.
// MODE 0: QKV  -> Cb[m,3072] = phi/mask per column third (extra=validf, bias=qkv_b)
// MODE 1: XRES -> Cf[m,N] = acc + bias + extra[m,N]   (out-proj + residual, Cf=d_out)
// MODE 2: GELU -> Cb[m,N] = bf16(gelu_exact(acc+bias))
// MODE 3: ADD  -> Cf[m,N] += acc + bias               (FFN2 accumulate into x)
template<int MODE>
__global__ __launch_bounds__(256,2) void gemm_bt(
    const unsigned short* __restrict__ A, const unsigned short* __restrict__ Bw,
    const float* __restrict__ bias, const float* __restrict__ extra,
    float* __restrict__ Cf, unsigned short* __restrict__ Cb,
    int M, int N, int K)
{
  __shared__ __align__(16) unsigned short As[128*64];
  __shared__ __align__(16) unsigned short Bs[128*64];
  const int tid = threadIdx.x;
  const int wave = tid>>6, lane = tid&63;
  const int wm = wave>>1, wn = wave&1;          // 2x2 wave grid, 64x64 per wave
  // XCD-aware remap (grids here always have gridDim.y==256, total%8==0)
  const int f   = blockIdx.y * gridDim.x + blockIdx.x;
  const int xcd = f & 7, kk = f >> 3;
  const int nx  = kk % gridDim.x;
  const int ny  = (kk / gridDim.x) * 8 + xcd;
  const int m0 = ny*128, n0 = nx*128;
  const int lrow = lane>>3;                     // 0..7 rows within a wave-op
  const int gcol = (((lane&7) ^ lrow))*8;       // swizzled global chunk for staging

  f32x4 acc[4][4];
  #pragma unroll
  for(int i=0;i<4;i++)
    #pragma unroll
    for(int j=0;j<4;j++) acc[i][j]=(f32x4)(0.f);

  const int ar = wm*64 + (lane&15);             // A frag row in tile
  const int br = wn*64 + (lane&15);             // B frag row in tile
  const int kc = lane>>4;                       // k chunk sub-index (0..3)
  const int xorv = lane&7;                      // row&7 == lane&7 for all frags

  for(int kt=0; kt<K; kt+=64){
    #pragma unroll
    for(int it=0; it<4; it++){
      int wo = wave*4+it;                       // wave-op 0..15, 8 rows each
      int r  = wo*8 + lrow;
      async16(A  + (size_t)(m0+r)*K + kt + gcol, (void*)&As[wo*512]);
      async16(Bw + (size_t)(n0+r)*K + kt + gcol, (void*)&Bs[wo*512]);
    }
    __syncthreads();   // compiler drains vmcnt before s_barrier -> tiles ready
    #pragma unroll
    for(int ks=0; ks<2; ks++){
      const int ch = ((ks*4 + kc) ^ xorv)*8;    // swizzled LDS chunk offset
      short8 a[4], b[4];
      #pragma unroll
      for(int i=0;i<4;i++){
        a[i]=*(const short8*)&As[(ar+i*16)*64 + ch];
        b[i]=*(const short8*)&Bs[(br+i*16)*64 + ch];
      }
      #pragma unroll
      for(int i=0;i<4;i++)
        #pragma unroll
        for(int j=0;j<4;j++)
          acc[i][j]=__builtin_amdgcn_mfma_f32_16x16x32_bf16(a[i],b[j],acc[i][j],0,0,0);
    }
    __syncthreads();
  }
  // epilogue: C/D layout col=lane&15, row=(lane>>4)*4+reg
  const int rbase = m0 + wm*64 + (lane>>4)*4;
  const int cbase = n0 + wn*64 + (lane&15);
  #pragma unroll
  for(int mi=0;mi<4;mi++){
    #pragma unroll
    for(int i=0;i<4;i++){
      int m = rbase + mi*16 + i;
      #pragma unroll
      for(int ni=0;ni<4;ni++){
        int n = cbase + ni*16;
        float v = acc[mi][ni][i] + bias[n];
        if(MODE==0){
          float valid = extra[m];
          int part = n>>10;                      // 0=q,1=k,2=v
          float p = (v>0.f)? (v+1.f) : __expf(v);// phi = elu+1
          float r = (part==0)? p : (part==1? p*valid : v*valid);
          Cb[(size_t)m*N + n] = f2b(r);
        } else if(MODE==1){
          size_t off=(size_t)m*N+n;
          Cf[off] = v + extra[off];
        } else if(MODE==2){
          float gl = 0.5f*v*(1.f+erff(v*0.70710678118654752f));
          Cb[(size_t)m*N+n] = f2b(gl);
        } else {
          size_t off=(size_t)m*N+n;
          Cf[off] += v;
        }
      }
    }
  }
}

// ---------------- kv = phi(k)^T v, z = sum phi(k), partial over 256-row chunks ----
__global__ __launch_bounds__(256) void kvz_partial_kernel(
    const unsigned short* __restrict__ qkv, float* __restrict__ kvp, float* __restrict__ zp)
{
  const int chunk = blockIdx.x;   // 0..15 (256 rows each)
  const int bh = blockIdx.y;      // 0..127
  const int b = bh>>4, h = bh&15;
  const int t = threadIdx.x;
  __shared__ float kfs[16][64];
  __shared__ float vs[16][64];
  float acc[4][4]={{0}}; float zacc[4]={0};
  const int td=t&15, te=t>>4;
  const int d0=td*4, e0=te*4;
  const int lr=t>>4, lc=(t&15)*4;
  for(int s=0;s<16;s++){
    size_t m  = (size_t)(b*SEQ + chunk*256 + s*16 + lr);
    size_t rb = m*3072 + (size_t)h*64;
    ushort4 k4 = *(const ushort4*)(qkv + rb + 1024 + lc);
    ushort4 v4 = *(const ushort4*)(qkv + rb + 2048 + lc);
    __syncthreads();
    kfs[lr][lc]=b2f(k4.x); kfs[lr][lc+1]=b2f(k4.y); kfs[lr][lc+2]=b2f(k4.z); kfs[lr][lc+3]=b2f(k4.w);
    vs [lr][lc]=b2f(v4.x); vs [lr][lc+1]=b2f(v4.y); vs [lr][lc+2]=b2f(v4.z); vs [lr][lc+3]=b2f(v4.w);
    __syncthreads();
    #pragma unroll
    for(int n=0;n<16;n++){
      float4 kq=*(const float4*)&kfs[n][d0];
      float4 vv=*(const float4*)&vs[n][e0];
      float kqa[4]={kq.x,kq.y,kq.z,kq.w};
      float vva[4]={vv.x,vv.y,vv.z,vv.w};
      #pragma unroll
      for(int i=0;i<4;i++)
        #pragma unroll
        for(int j=0;j<4;j++) acc[i][j]+=kqa[i]*vva[j];
      if(te==0){ zacc[0]+=kq.x; zacc[1]+=kq.y; zacc[2]+=kq.z; zacc[3]+=kq.w; }
    }
  }
  const int pidx = bh*16 + chunk;
  float* kvd = kvp + (size_t)pidx*4096;
  #pragma unroll
  for(int i=0;i<4;i++){
    float4 o={acc[i][0],acc[i][1],acc[i][2],acc[i][3]};
    *(float4*)(kvd + (d0+i)*64 + e0)=o;
  }
  if(te==0){
    float4 o={zacc[0],zacc[1],zacc[2],zacc[3]};
    *(float4*)(zp + (size_t)pidx*64 + d0)=o;
  }
}

__global__ void kvz_reduce_kernel(const float* __restrict__ kvp, const float* __restrict__ zp,
                                  float* __restrict__ kv, float* __restrict__ z){
  int bh = blockIdx.x, t = threadIdx.x;
  for(int j=t; j<4096; j+=256){
    float s=0;
    for(int c=0;c<16;c++) s += kvp[((size_t)bh*16+c)*4096 + j];
    kv[(size_t)bh*4096 + j] = s;
  }
  if(t<64){
    float s=0;
    for(int c=0;c<16;c++) s += zp[((size_t)bh*16+c)*64 + t];
    z[bh*64+t]=s;
  }
}

// ---------------- y = (qf @ kv) / max(qf . z, eps) -> bf16 [MTOK, 1024] ----------
__global__ __launch_bounds__(256) void y_kernel(
    const unsigned short* __restrict__ qkv, const float* __restrict__ kv,
    const float* __restrict__ z, unsigned short* __restrict__ ybuf)
{
  const int nch = blockIdx.x;   // 0..63 (64 rows each)
  const int bh  = blockIdx.y;   // 0..127
  const int b = bh>>4, h = bh&15;
  const int t = threadIdx.x;
  __shared__ float kvs[64][64];
  __shared__ float qfs[64][68];  // padded: breaks 4-way bank conflict on column reads
  __shared__ float zs[64];
  // stage kv (fp32) and z
  for(int j=t*4; j<4096; j+=1024){
    float4 vv=*(const float4*)(kv+(size_t)bh*4096+j);
    ((float*)kvs)[j]=vv.x; ((float*)kvs)[j+1]=vv.y; ((float*)kvs)[j+2]=vv.z; ((float*)kvs)[j+3]=vv.w;
  }
  if(t<64) zs[t]=z[bh*64+t];
  // stage qf tile (64 rows x 64 d)
  for(int s=0;s<4;s++){
    int row=s*16+(t>>4), col=(t&15)*4;
    size_t m=(size_t)(b*SEQ+nch*64+row);
    ushort4 q4=*(const ushort4*)(qkv+m*3072+(size_t)h*64+col);
    qfs[row][col]=b2f(q4.x); qfs[row][col+1]=b2f(q4.y); qfs[row][col+2]=b2f(q4.z); qfs[row][col+3]=b2f(q4.w);
  }
  __syncthreads();
  const int tn=t>>4, te=t&15;
  const int nr0=tn*4, e0=te*4;
  float acc[4][4]={{0}}; float den[4]={0};
  #pragma unroll 4
  for(int d=0;d<64;d++){
    float4 kv4=*(const float4*)&kvs[d][e0];
    float zd=zs[d];
    #pragma unroll
    for(int i=0;i<4;i++){
      float q=qfs[nr0+i][d];
      acc[i][0]+=q*kv4.x; acc[i][1]+=q*kv4.y; acc[i][2]+=q*kv4.z; acc[i][3]+=q*kv4.w;
      den[i]+=q*zd;
    }
  }
  #pragma unroll
  for(int i=0;i<4;i++){
    float inv=1.f/fmaxf(den[i],1e-6f);
    ushort4 o;
    o.x=f2b(acc[i][0]*inv); o.y=f2b(acc[i][1]*inv); o.z=f2b(acc[i][2]*inv); o.w=f2b(acc[i][3]*inv);
    size_t m=(size_t)(b*SEQ+nch*64+nr0+i);
    *(ushort4*)(ybuf+m*1024+(size_t)h*64+e0)=o;
  }
}

extern "C" void kernel_launch(void* const* d_in, const int* in_sizes, int n_in,
                              void* d_out, int out_size, void* d_ws, size_t ws_size,
                              hipStream_t stream)
{
  const float* src   = (const float*)d_in[0];
  const void*  mask  = d_in[1];
  const float* qkv_w = (const float*)d_in[2];
  const float* qkv_b = (const float*)d_in[3];
  const float* out_w = (const float*)d_in[4];
  const float* out_b = (const float*)d_in[5];
  const float* w1    = (const float*)d_in[6];
  const float* b1    = (const float*)d_in[7];
  const float* w2    = (const float*)d_in[8];
  const float* b2    = (const float*)d_in[9];
  const float* ln1g  = (const float*)d_in[10];
  const float* ln1b  = (const float*)d_in[11];
  const float* ln2g  = (const float*)d_in[12];
  const float* ln2b  = (const float*)d_in[13];
  float* out = (float*)d_out;
  char* ws = (char*)d_ws;

  // workspace layout (~346 MiB total)
  size_t o = 0;
  int* flag = (int*)(ws);                         o += 256;
  float* validf = (float*)(ws+o);                 o += (size_t)MTOK*4;
  unsigned short* wqb = (unsigned short*)(ws+o);  o += (size_t)3072*1024*2;
  unsigned short* wob = (unsigned short*)(ws+o);  o += (size_t)1024*1024*2;
  unsigned short* w1b = (unsigned short*)(ws+o);  o += (size_t)4096*1024*2;
  unsigned short* w2b = (unsigned short*)(ws+o);  o += (size_t)1024*4096*2;
  unsigned short* bufA = (unsigned short*)(ws+o); o += (size_t)MTOK*1024*2;       // ln1 -> y -> ln2
  char* R = ws+o;                                 o += (size_t)MTOK*4096*2;       // qkv (201MB) then h (268MB)
  unsigned short* qkvbuf = (unsigned short*)R;
  float* kvp = (float*)(R + (size_t)MTOK*3072*2);                                  // fits in R tail
  float* zp  = (float*)(R + (size_t)MTOK*3072*2 + (size_t)2048*4096*4);
  unsigned short* hbuf = (unsigned short*)R;
  float* kv = (float*)(ws+o);                     o += (size_t)128*4096*4;
  float* zv = (float*)(ws+o);                     o += (size_t)128*64*4;

  detect_mask_kernel<<<1,256,0,stream>>>((const unsigned int*)mask, flag);
  decode_mask_kernel<<<MTOK/256,256,0,stream>>>(mask, flag, validf);
  cast_bf16_kernel<<<3072,256,0,stream>>>(qkv_w, wqb, 3072*1024);
  cast_bf16_kernel<<<1024,256,0,stream>>>(out_w, wob, 1024*1024);
  cast_bf16_kernel<<<4096,256,0,stream>>>(w1,  w1b, 4096*1024);
  cast_bf16_kernel<<<8192,256,0,stream>>>(w2,  w2b, 1024*4096);

  ln_kernel<<<MTOK,256,0,stream>>>(src, ln1g, ln1b, bufA);
  gemm_bt<0><<<dim3(3072/128, MTOK/128),256,0,stream>>>(bufA, wqb, qkv_b, validf, nullptr, qkvbuf, MTOK,3072,1024);
  kvz_partial_kernel<<<dim3(16,128),256,0,stream>>>(qkvbuf, kvp, zp);
  kvz_reduce_kernel<<<128,256,0,stream>>>(kvp, zp, kv, zv);
  y_kernel<<<dim3(64,128),256,0,stream>>>(qkvbuf, kv, zv, bufA);
  gemm_bt<1><<<dim3(1024/128, MTOK/128),256,0,stream>>>(bufA, wob, out_b, src, out, nullptr, MTOK,1024,1024);
  ln_kernel<<<MTOK,256,0,stream>>>(out, ln2g, ln2b, bufA);
  gemm_bt<2><<<dim3(4096/128, MTOK/128),256,0,stream>>>(bufA, w1b, b1, nullptr, nullptr, hbuf, MTOK,4096,1024);
  gemm_bt<3><<<dim3(1024/128, MTOK/128),256,0,stream>>>(hbuf, w2b, b2, nullptr, out, nullptr, MTOK,1024,4096);
}